// Round 2
// baseline (506.572 us; speedup 1.0000x reference)
//
#include <hip/hip_runtime.h>
#include <stdint.h>

typedef __attribute__((ext_vector_type(8))) short short8;
typedef __attribute__((ext_vector_type(4))) float floatx4;
typedef __attribute__((ext_vector_type(4))) unsigned short u16x4;

#define Hh 384
#define Ww 384
#define Cc 11
#define Nn 32
#define PITCH 72  // 64 + 8 pad bf16 elems; 144 B rows: 16B-aligned

__device__ __forceinline__ unsigned short f2bf(float f) {
  union { float f; uint32_t u; } z; z.f = f;
  return (unsigned short)(z.u >> 16);
}
__device__ __forceinline__ float bf2f(unsigned short b) {
  union { uint32_t u; float f; } z; z.u = ((uint32_t)b) << 16;
  return z.f;
}

// Raw barrier WITHOUT __syncthreads' vmcnt(0) drain: LDS ops must be complete
// (my stage-writes visible to others; my frag-reads done so others may
// overwrite), but global prefetch loads stay in flight across it.
#define BAR() do {                                          \
    asm volatile("s_waitcnt lgkmcnt(0)" ::: "memory");      \
    __builtin_amdgcn_s_barrier();                           \
    asm volatile("" ::: "memory");                          \
  } while (0)

__global__ __launch_bounds__(256, 4)
void center_loss(const float* __restrict__ X, const float* __restrict__ Cen,
                 const int* __restrict__ Lab, float* __restrict__ Out) {
  // Double-buffered bf16 tiles: stage tile i+1 into buf[(i+1)&1] while
  // MFMA-reading tile i from buf[i&1].
  __shared__ __align__(16) unsigned short Alds[2][64 * PITCH];  // A[i][k]  (x rows)
  __shared__ __align__(16) unsigned short Blds[2][64 * PITCH];  // Bt[j][k] (centers cols)
  __shared__ float red[4];

  // XCD swizzle: all 36 blocks of one n share an XCD (per-channel set fits L2).
  const int bx   = blockIdx.x;
  const int xcd  = bx & 7;
  const int slot = bx >> 3;
  const int grp  = slot / 36;
  const int t36  = slot - grp * 36;
  const int n    = xcd + (grp << 3);
  const int ib = t36 / 6;
  const int jb = t36 - ib * 6;
  const int i0 = ib << 6, j0 = jb << 6;

  const int t   = threadIdx.x;
  const int l   = t & 63;
  const int w   = t >> 6;
  const int wr  = (w >> 1) << 5;
  const int wc  = (w & 1) << 5;
  const int q4  = l >> 4;
  const int l16 = l & 15;
  const int sr  = t >> 4;   // A staging: row base
  const int sa  = t & 15;   // A staging: 4-col segment
  const int jp  = t & 31;   // B staging: j pair (rows 2jp, 2jp+1 of Bt)
  const int kc  = t >> 5;   // B staging: k octet (cols 8kc..8kc+7)

  const size_t plane = (size_t)Hh * Ww;
  const float* xrow = X   + (size_t)n * Cc * plane + (size_t)(i0 + sr) * Ww + (sa << 2);
  const float* crow = Cen + (size_t)n * Cc * plane + (size_t)(kc << 3) * Ww + j0 + (jp << 1);

  float m[16], s[16];
#pragma unroll
  for (int i = 0; i < 16; ++i) { m[i] = -3.0e38f; s[i] = 0.0f; }

  floatx4 acc[2][2];
#pragma unroll
  for (int a = 0; a < 2; ++a)
#pragma unroll
    for (int b = 0; b < 2; ++b) acc[a][b] = (floatx4){0.f, 0.f, 0.f, 0.f};

  // One-deep register prefetch (32 VGPR): holds tile i+1 during iteration i's
  // compute; refilled with tile i+2 right after staging.
  float4 pa[4];
  float2 pb[8];

#define LOADT(CC, KK) do {                                                     \
    const float* ap_ = xrow + (size_t)(CC) * plane + ((KK) << 6);              \
    pa[0] = *reinterpret_cast<const float4*>(ap_);                             \
    pa[1] = *reinterpret_cast<const float4*>(ap_ + 16 * Ww);                   \
    pa[2] = *reinterpret_cast<const float4*>(ap_ + 32 * Ww);                   \
    pa[3] = *reinterpret_cast<const float4*>(ap_ + 48 * Ww);                   \
    const float* bp_ = crow + (size_t)(CC) * plane + (size_t)((KK) << 6) * Ww; \
    _Pragma("unroll")                                                          \
    for (int u_ = 0; u_ < 8; ++u_)                                             \
      pb[u_] = *reinterpret_cast<const float2*>(bp_ + (size_t)u_ * Ww);        \
  } while (0)

#define STAGE(WB) do {                                                         \
    _Pragma("unroll")                                                          \
    for (int p_ = 0; p_ < 4; ++p_) {                                           \
      u16x4 pk_;                                                               \
      pk_.x = f2bf(pa[p_].x); pk_.y = f2bf(pa[p_].y);                          \
      pk_.z = f2bf(pa[p_].z); pk_.w = f2bf(pa[p_].w);                          \
      *reinterpret_cast<u16x4*>(&Alds[WB][(sr + 16 * p_) * PITCH + (sa << 2)]) = pk_; \
    }                                                                          \
    short8 s0_, s1_;                                                           \
    _Pragma("unroll")                                                          \
    for (int u_ = 0; u_ < 8; ++u_) {                                           \
      s0_[u_] = (short)f2bf(pb[u_].x);                                         \
      s1_[u_] = (short)f2bf(pb[u_].y);                                         \
    }                                                                          \
    *reinterpret_cast<short8*>(&Blds[WB][(jp << 1) * PITCH + (kc << 3)]) = s0_;       \
    *reinterpret_cast<short8*>(&Blds[WB][((jp << 1) + 1) * PITCH + (kc << 3)]) = s1_; \
  } while (0)

  // res = x^2 + c^2 - 2*mm carried as acc = mm - 0.5*(x^2 + c^2); res = -2*acc.
#define COMPUTE(RB) do {                                                       \
    if (kb == jb) { /* A tile holds x[i0..][j0..j0+63] */                      \
      _Pragma("unroll") for (int fr_ = 0; fr_ < 2; ++fr_)                      \
      _Pragma("unroll") for (int fc_ = 0; fc_ < 2; ++fc_)                      \
      _Pragma("unroll") for (int r_ = 0; r_ < 4; ++r_) {                       \
        const int pr_ = wr + (fr_ << 4) + (q4 << 2) + r_;                      \
        const int pc_ = wc + (fc_ << 4) + l16;                                 \
        float xv_ = bf2f(Alds[RB][pr_ * PITCH + pc_]);                         \
        acc[fr_][fc_][r_] -= 0.5f * xv_ * xv_;                                 \
      }                                                                        \
    }                                                                          \
    if (kb == ib) { /* Bt tile holds centers[i0..i0+63][j0..j0+63]^T */        \
      _Pragma("unroll") for (int fr_ = 0; fr_ < 2; ++fr_)                      \
      _Pragma("unroll") for (int fc_ = 0; fc_ < 2; ++fc_)                      \
      _Pragma("unroll") for (int r_ = 0; r_ < 4; ++r_) {                       \
        const int pr_ = wr + (fr_ << 4) + (q4 << 2) + r_;                      \
        const int pc_ = wc + (fc_ << 4) + l16;                                 \
        float cv_ = bf2f(Blds[RB][pc_ * PITCH + pr_]);                         \
        acc[fr_][fc_][r_] -= 0.5f * cv_ * cv_;                                 \
      }                                                                        \
    }                                                                          \
    _Pragma("unroll") for (int ks_ = 0; ks_ < 2; ++ks_) {                      \
      const int ko_ = (ks_ << 5) + (q4 << 3);                                  \
      short8 a0_ = *reinterpret_cast<const short8*>(&Alds[RB][(wr +      l16) * PITCH + ko_]); \
      short8 a1_ = *reinterpret_cast<const short8*>(&Alds[RB][(wr + 16 + l16) * PITCH + ko_]); \
      short8 b0_ = *reinterpret_cast<const short8*>(&Blds[RB][(wc +      l16) * PITCH + ko_]); \
      short8 b1_ = *reinterpret_cast<const short8*>(&Blds[RB][(wc + 16 + l16) * PITCH + ko_]); \
      acc[0][0] = __builtin_amdgcn_mfma_f32_16x16x32_bf16(a0_, b0_, acc[0][0], 0, 0, 0); \
      acc[0][1] = __builtin_amdgcn_mfma_f32_16x16x32_bf16(a0_, b1_, acc[0][1], 0, 0, 0); \
      acc[1][0] = __builtin_amdgcn_mfma_f32_16x16x32_bf16(a1_, b0_, acc[1][0], 0, 0, 0); \
      acc[1][1] = __builtin_amdgcn_mfma_f32_16x16x32_bf16(a1_, b1_, acc[1][1], 0, 0, 0); \
    }                                                                          \
    if (kb == 5) { /* channel boundary: online softmax update */               \
      _Pragma("unroll") for (int fr_ = 0; fr_ < 2; ++fr_)                      \
      _Pragma("unroll") for (int fc_ = 0; fc_ < 2; ++fc_)                      \
      _Pragma("unroll") for (int r_ = 0; r_ < 4; ++r_) {                       \
        const int idx_ = ((fr_ << 1) + fc_) * 4 + r_;                          \
        float res_ = -2.0f * acc[fr_][fc_][r_];                                \
        float mi_ = m[idx_];                                                   \
        if (res_ <= mi_) {                                                     \
          s[idx_] += __expf(res_ - mi_);                                       \
        } else {                                                               \
          s[idx_] = s[idx_] * __expf(mi_ - res_) + 1.0f;                       \
          m[idx_] = res_;                                                      \
        }                                                                      \
        acc[fr_][fc_][r_] = 0.0f;                                              \
      }                                                                        \
    }                                                                          \
    ++kb; if (kb == 6) kb = 0;                                                 \
  } while (0)

  // ---- prologue: load+stage tile0 into buf0; prefetch tile1 into regs ----
  LOADT(0, 0);
  STAGE(0);
  LOADT(0, 1);
  BAR();

  int kb = 0;            // k-block (within channel) of the tile being computed
  int kbL = 2, cL = 0;   // next tile to load (tile 2)

  // 66 tiles total. Paired iterations i = 2*mi, 2*mi+1 for static buf indices.
  for (int mi = 0; mi < 32; ++mi) {
    // even i: stage tile i+1 -> buf1, refill regs with tile i+2, compute buf0
    STAGE(1);
    LOADT(cL, kbL);
    ++kbL; if (kbL == 6) { kbL = 0; ++cL; }
    COMPUTE(0);
    BAR();
    // odd i: stage tile i+2 -> buf0, refill regs with tile i+3, compute buf1
    STAGE(0);
    LOADT(cL, kbL);
    ++kbL; if (kbL == 6) { kbL = 0; ++cL; }
    COMPUTE(1);
    BAR();
  }
  // i = 64: stage tile 65 -> buf1, compute tile 64 from buf0
  STAGE(1);
  COMPUTE(0);
  BAR();
  // i = 65: compute tile 65 from buf1 (kb==5 -> final softmax update)
  COMPUTE(1);

  // ---- max(softmax) = 1/s ; weight by label; clip; reduce ----
  float local = 0.0f;
  const int* lb = Lab + (size_t)n * plane;
#pragma unroll
  for (int fr = 0; fr < 2; ++fr)
#pragma unroll
    for (int fc = 0; fc < 2; ++fc)
#pragma unroll
      for (int r = 0; r < 4; ++r) {
        const int idx = ((fr << 1) + fc) * 4 + r;
        const int pr = i0 + wr + (fr << 4) + (q4 << 2) + r;
        const int pc = j0 + wc + (fc << 4) + l16;
        float val = 1.0f / s[idx];
        float d = val * (float)lb[pr * Ww + pc];
        d = fminf(fmaxf(d, 1e-12f), 1e12f);
        local += d;
      }
#pragma unroll
  for (int off = 32; off > 0; off >>= 1) local += __shfl_down(local, off, 64);
  if (l == 0) red[w] = local;
  __syncthreads();
  if (t == 0) {
    float bs = (red[0] + red[1] + red[2] + red[3]) * (1.0f / 4718592.0f);
    atomicAdd(Out, bs);
  }
}

extern "C" void kernel_launch(void* const* d_in, const int* in_sizes, int n_in,
                              void* d_out, int out_size, void* d_ws, size_t ws_size,
                              hipStream_t stream) {
  const float* X   = (const float*)d_in[0];
  const float* Cen = (const float*)d_in[1];
  const int*   Lab = (const int*)d_in[2];
  float* Out = (float*)d_out;
  hipMemsetAsync(Out, 0, (size_t)out_size * sizeof(float), stream);
  hipLaunchKernelGGL(center_loss, dim3(Nn * 36), dim3(256), 0, stream,
                     X, Cen, Lab, Out);
}